// Round 1
// baseline (3172.024 us; speedup 1.0000x reference)
//
#include <hip/hip_runtime.h>
#include <cstddef>

#define HH     256
#define LLEN   256
#define BATCH  4
#define VOCAB  32000
#define EMB    256
#define NB     8
#define KDIM   2048        /* H*NB */
#define NROWS  1024        /* B*L  */
#define NCOL   4096        /* 2*KDIM */

__device__ __forceinline__ float cl3_sign(int a, int b) {
  int x = a >> 1, p = 0;
  while (x) { p ^= __popc(x & b) & 1; x >>= 1; }
  return p ? -1.f : 1.f;   // metric all +1 for Cl(3,0)
}

__device__ __forceinline__ float clipf(float v) { return fminf(fmaxf(v, 0.f), 1.f); }

// MREC[row=(h,i)][col]: col<2048 -> M1[(h,i),(g,k)] = Wrec[g,h,i^k]*s(i,i^k)
//                       col>=2048 -> M2[(h,i),(p,q)] = s(i,i)*s(q,q^i)*Wrec[h,p,q^i]
__global__ void k_build_mrec(const float* __restrict__ Wrec, float* __restrict__ M) {
  int idx = blockIdx.x * blockDim.x + threadIdx.x;
  int col = idx & (NCOL - 1);
  int row = idx >> 12;
  int h = row >> 3, i = row & 7;
  float v;
  if (col < KDIM) {
    int g = col >> 3, k = col & 7;
    int j = i ^ k;
    v = Wrec[(size_t)g * KDIM + h * NB + j] * cl3_sign(i, j);
  } else {
    int c = col - KDIM;
    int p = c >> 3, q = c & 7;
    int j = q ^ i;
    v = cl3_sign(i, i) * cl3_sign(q, j) * Wrec[(size_t)h * KDIM + p * NB + j];
  }
  M[idx] = v;
}

// input_mv[r][h*8+i] = sum_d emb[x[r]][d] * Win[h][d][i]; one block = 4 rows
__global__ __launch_bounds__(256) void k_input_mv(const int* __restrict__ x,
                                                  const float* __restrict__ emb,
                                                  const float* __restrict__ Win,
                                                  float* __restrict__ out) {
  __shared__ float se[4][EMB];
  int r0 = blockIdx.x * 4;
  int t = threadIdx.x;
  for (int rr = 0; rr < 4; ++rr) {
    int tok = x[r0 + rr];
    se[rr][t] = emb[(size_t)tok * EMB + t];
  }
  __syncthreads();
  float acc[4][8];
#pragma unroll
  for (int rr = 0; rr < 4; ++rr)
#pragma unroll
    for (int i = 0; i < 8; ++i) acc[rr][i] = 0.f;
  const float* wrow = Win + (size_t)t * KDIM;
  for (int d = 0; d < EMB; ++d) {
    float4 w0 = *(const float4*)(wrow + d * 8);
    float4 w1 = *(const float4*)(wrow + d * 8 + 4);
#pragma unroll
    for (int rr = 0; rr < 4; ++rr) {
      float e = se[rr][d];
      acc[rr][0] += e * w0.x; acc[rr][1] += e * w0.y;
      acc[rr][2] += e * w0.z; acc[rr][3] += e * w0.w;
      acc[rr][4] += e * w1.x; acc[rr][5] += e * w1.y;
      acc[rr][6] += e * w1.z; acc[rr][7] += e * w1.w;
    }
  }
  for (int rr = 0; rr < 4; ++rr) {
    float4* o = (float4*)(out + (size_t)(r0 + rr) * KDIM + t * 8);
    o[0] = make_float4(acc[rr][0], acc[rr][1], acc[rr][2], acc[rr][3]);
    o[1] = make_float4(acc[rr][4], acc[rr][5], acc[rr][6], acc[rr][7]);
  }
}

// RF[r][0:4096] = clip(H[r]) @ MREC   (fp32 64x64x32 tile)
__global__ __launch_bounds__(256) void k_gemm_rf(const float* __restrict__ Hb,
                                                 const float* __restrict__ M,
                                                 float* __restrict__ RF) {
  __shared__ float As[32][68];
  __shared__ float Bs[32][68];
  const int t = threadIdx.x;
  const int tx = t & 15, ty = t >> 4;
  const int row0 = blockIdx.y * 64, col0 = blockIdx.x * 64;
  const int ar = t >> 3, ac = (t & 7) << 2;
  const int br = t >> 4, bc = (t & 15) << 2;
  float acc[4][4] = {};
  for (int k0 = 0; k0 < KDIM; k0 += 32) {
    float4 a0 = *(const float4*)(Hb + (size_t)(row0 + ar) * KDIM + k0 + ac);
    float4 a1 = *(const float4*)(Hb + (size_t)(row0 + ar + 32) * KDIM + k0 + ac);
    float4 b0 = *(const float4*)(M + (size_t)(k0 + br) * NCOL + col0 + bc);
    float4 b1 = *(const float4*)(M + (size_t)(k0 + br + 16) * NCOL + col0 + bc);
    As[ac + 0][ar] = clipf(a0.x); As[ac + 1][ar] = clipf(a0.y);
    As[ac + 2][ar] = clipf(a0.z); As[ac + 3][ar] = clipf(a0.w);
    As[ac + 0][ar + 32] = clipf(a1.x); As[ac + 1][ar + 32] = clipf(a1.y);
    As[ac + 2][ar + 32] = clipf(a1.z); As[ac + 3][ar + 32] = clipf(a1.w);
    *(float4*)&Bs[br][bc] = b0;
    *(float4*)&Bs[br + 16][bc] = b1;
    __syncthreads();
#pragma unroll
    for (int kk = 0; kk < 32; ++kk) {
      float4 av = *(const float4*)&As[kk][ty << 2];
      float4 bv = *(const float4*)&Bs[kk][tx << 2];
      acc[0][0] += av.x * bv.x; acc[0][1] += av.x * bv.y; acc[0][2] += av.x * bv.z; acc[0][3] += av.x * bv.w;
      acc[1][0] += av.y * bv.x; acc[1][1] += av.y * bv.y; acc[1][2] += av.y * bv.z; acc[1][3] += av.y * bv.w;
      acc[2][0] += av.z * bv.x; acc[2][1] += av.z * bv.y; acc[2][2] += av.z * bv.z; acc[2][3] += av.z * bv.w;
      acc[3][0] += av.w * bv.x; acc[3][1] += av.w * bv.y; acc[3][2] += av.w * bv.z; acc[3][3] += av.w * bv.w;
    }
    __syncthreads();
  }
#pragma unroll
  for (int i = 0; i < 4; ++i) {
    *(float4*)(RF + (size_t)(row0 + (ty << 2) + i) * NCOL + col0 + (tx << 2)) =
        make_float4(acc[i][0], acc[i][1], acc[i][2], acc[i][3]);
  }
}

// h <- h - 0.1*(h - drho(h)*(inmv*sq + rec_prev*sq + fwd_next))
__global__ void k_update(float* __restrict__ Hb, const float* __restrict__ Imv,
                         const float* __restrict__ RF) {
  int idx = blockIdx.x * blockDim.x + threadIdx.x;
  int r = idx >> 11;
  int c = idx & 2047;
  int m = r & (LLEN - 1);
  int q = c & 7;
  float h = Hb[idx];
  float dr = (h > 0.f && h < 1.f) ? 1.f : ((h == 0.f || h == 1.f) ? 0.5f : 0.f);
  float sq = cl3_sign(q, q);
  float f = Imv[idx] * sq;
  if (m >= 1)        f += RF[(size_t)(r - 1) * NCOL + c] * sq;
  if (m < LLEN - 1)  f += RF[(size_t)(r + 1) * NCOL + KDIM + c];
  Hb[idx] = h - 0.1f * (h - dr * f);
}

// logits[r][v] = sum_k (H[r][k]*bsign(k&7)) * Wout[v][k]
__global__ __launch_bounds__(256) void k_gemm_logits(const float* __restrict__ Hb,
                                                     const float* __restrict__ Wout,
                                                     float* __restrict__ Cout) {
  __shared__ float As[32][68];
  __shared__ float Bs[32][68];
  const int t = threadIdx.x;
  const int tx = t & 15, ty = t >> 4;
  const int row0 = blockIdx.x * 64, col0 = blockIdx.y * 64;
  const int ar = t >> 3, ac = (t & 7) << 2;
  const int ib = ac & 7;  // 0 or 4
  const float s0 = cl3_sign(ib + 0, ib + 0), s1 = cl3_sign(ib + 1, ib + 1);
  const float s2 = cl3_sign(ib + 2, ib + 2), s3 = cl3_sign(ib + 3, ib + 3);
  float acc[4][4] = {};
  for (int k0 = 0; k0 < KDIM; k0 += 32) {
    float4 a0 = *(const float4*)(Hb + (size_t)(row0 + ar) * KDIM + k0 + ac);
    float4 a1 = *(const float4*)(Hb + (size_t)(row0 + ar + 32) * KDIM + k0 + ac);
    float4 b0 = *(const float4*)(Wout + (size_t)(col0 + ar) * KDIM + k0 + ac);
    float4 b1 = *(const float4*)(Wout + (size_t)(col0 + ar + 32) * KDIM + k0 + ac);
    As[ac + 0][ar] = a0.x * s0; As[ac + 1][ar] = a0.y * s1;
    As[ac + 2][ar] = a0.z * s2; As[ac + 3][ar] = a0.w * s3;
    As[ac + 0][ar + 32] = a1.x * s0; As[ac + 1][ar + 32] = a1.y * s1;
    As[ac + 2][ar + 32] = a1.z * s2; As[ac + 3][ar + 32] = a1.w * s3;
    Bs[ac + 0][ar] = b0.x; Bs[ac + 1][ar] = b0.y;
    Bs[ac + 2][ar] = b0.z; Bs[ac + 3][ar] = b0.w;
    Bs[ac + 0][ar + 32] = b1.x; Bs[ac + 1][ar + 32] = b1.y;
    Bs[ac + 2][ar + 32] = b1.z; Bs[ac + 3][ar + 32] = b1.w;
    __syncthreads();
#pragma unroll
    for (int kk = 0; kk < 32; ++kk) {
      float4 av = *(const float4*)&As[kk][ty << 2];
      float4 bv = *(const float4*)&Bs[kk][tx << 2];
      acc[0][0] += av.x * bv.x; acc[0][1] += av.x * bv.y; acc[0][2] += av.x * bv.z; acc[0][3] += av.x * bv.w;
      acc[1][0] += av.y * bv.x; acc[1][1] += av.y * bv.y; acc[1][2] += av.y * bv.z; acc[1][3] += av.y * bv.w;
      acc[2][0] += av.z * bv.x; acc[2][1] += av.z * bv.y; acc[2][2] += av.z * bv.z; acc[2][3] += av.z * bv.w;
      acc[3][0] += av.w * bv.x; acc[3][1] += av.w * bv.y; acc[3][2] += av.w * bv.z; acc[3][3] += av.w * bv.w;
    }
    __syncthreads();
  }
#pragma unroll
  for (int i = 0; i < 4; ++i) {
    *(float4*)(Cout + (size_t)(row0 + (ty << 2) + i) * VOCAB + col0 + (tx << 2)) =
        make_float4(acc[i][0], acc[i][1], acc[i][2], acc[i][3]);
  }
}

extern "C" void kernel_launch(void* const* d_in, const int* in_sizes, int n_in,
                              void* d_out, int out_size, void* d_ws, size_t ws_size,
                              hipStream_t stream) {
  const int*   x    = (const int*)d_in[0];
  const float* emb  = (const float*)d_in[1];
  const float* Win  = (const float*)d_in[2];
  const float* Wrec = (const float*)d_in[3];
  const float* Wout = (const float*)d_in[4];
  float* logits = (float*)d_out;

  float* ws   = (float*)d_ws;
  float* Hbuf = ws;                 // 2,097,152 f
  float* Imv  = ws + 2097152;       // 2,097,152 f
  float* RF   = ws + 4194304;       // 4,194,304 f
  float* MREC = ws + 8388608;       // 8,388,608 f  (total 64 MB)

  hipMemsetAsync(Hbuf, 0, (size_t)2097152 * sizeof(float), stream);
  k_build_mrec<<<32768, 256, 0, stream>>>(Wrec, MREC);
  k_input_mv<<<256, 256, 0, stream>>>(x, emb, Win, Imv);
  for (int it = 0; it < 5; ++it) {
    k_gemm_rf<<<dim3(64, 16), 256, 0, stream>>>(Hbuf, MREC, RF);
    k_update<<<8192, 256, 0, stream>>>(Hbuf, Imv, RF);
  }
  k_gemm_logits<<<dim3(16, 500), 256, 0, stream>>>(Hbuf, Wout, logits);
}

// Round 2
// 1188.532 us; speedup vs baseline: 2.6689x; 2.6689x over previous
//
#include <hip/hip_runtime.h>
#include <cstddef>

#define VOCAB  32000
#define EMB    256
#define NB     8
#define KDIM   2048        /* H*NB */
#define NROWS  1024        /* B*L  */
#define NCOL   4096        /* 2*KDIM */
#define LLEN   256

typedef __attribute__((ext_vector_type(8))) short short8;
typedef __attribute__((ext_vector_type(4))) float f32x4;

__device__ __forceinline__ float cl3_sign(int a, int b) {
  int x = a >> 1, p = 0;
  while (x) { p ^= __popc(x & b) & 1; x >>= 1; }
  return p ? -1.f : 1.f;   // metric all +1 for Cl(3,0)
}

__device__ __forceinline__ float clipf(float v) { return fminf(fmaxf(v, 0.f), 1.f); }

__device__ __forceinline__ unsigned short f2bf(float f) {
  unsigned u = __float_as_uint(f);
  u += 0x7FFF + ((u >> 16) & 1);           // round-to-nearest-even
  return (unsigned short)(u >> 16);
}
__device__ __forceinline__ float bf2f(unsigned short h) {
  return __uint_as_float(((unsigned)h) << 16);
}

// MRT[n][k]  (B^T layout for the GEMM), n in [0,4096), k in [0,2048)
// k=(h,i) K-index; n<2048 -> (g,kb): Wrec[g,h,i^kb]*s(i,i^kb)
// n>=2048 -> (p,q): s(i,i)*s(q,q^i)*Wrec[h,p,q^i]
__global__ void k_build_mrt(const float* __restrict__ Wrec, float* __restrict__ M) {
  int idx = blockIdx.x * blockDim.x + threadIdx.x;
  int k = idx & (KDIM - 1);
  int n = idx >> 11;
  int h = k >> 3, i = k & 7;
  float v;
  if (n < KDIM) {
    int g = n >> 3, kb = n & 7;
    int j = i ^ kb;
    v = Wrec[(size_t)g * KDIM + h * NB + j] * cl3_sign(i, j);
  } else {
    int c = n - KDIM;
    int p = c >> 3, q = c & 7;
    int j = q ^ i;
    v = cl3_sign(i, i) * cl3_sign(q, j) * Wrec[(size_t)h * KDIM + p * NB + j];
  }
  M[idx] = v;
}

// input_mv[r][h*8+i] = sum_d emb[x[r]][d] * Win[h][d][i]; one block = 4 rows
__global__ __launch_bounds__(256) void k_input_mv(const int* __restrict__ x,
                                                  const float* __restrict__ emb,
                                                  const float* __restrict__ Win,
                                                  float* __restrict__ out) {
  __shared__ float se[4][EMB];
  int r0 = blockIdx.x * 4;
  int t = threadIdx.x;
  for (int rr = 0; rr < 4; ++rr) {
    int tok = x[r0 + rr];
    se[rr][t] = emb[(size_t)tok * EMB + t];
  }
  __syncthreads();
  float acc[4][8];
#pragma unroll
  for (int rr = 0; rr < 4; ++rr)
#pragma unroll
    for (int i = 0; i < 8; ++i) acc[rr][i] = 0.f;
  const float* wrow = Win + (size_t)t * KDIM;
  for (int d = 0; d < EMB; ++d) {
    float4 w0 = *(const float4*)(wrow + d * 8);
    float4 w1 = *(const float4*)(wrow + d * 8 + 4);
#pragma unroll
    for (int rr = 0; rr < 4; ++rr) {
      float e = se[rr][d];
      acc[rr][0] += e * w0.x; acc[rr][1] += e * w0.y;
      acc[rr][2] += e * w0.z; acc[rr][3] += e * w0.w;
      acc[rr][4] += e * w1.x; acc[rr][5] += e * w1.y;
      acc[rr][6] += e * w1.z; acc[rr][7] += e * w1.w;
    }
  }
  for (int rr = 0; rr < 4; ++rr) {
    float4* o = (float4*)(out + (size_t)(r0 + rr) * KDIM + t * 8);
    o[0] = make_float4(acc[rr][0], acc[rr][1], acc[rr][2], acc[rr][3]);
    o[1] = make_float4(acc[rr][4], acc[rr][5], acc[rr][6], acc[rr][7]);
  }
}

// C[M,N] = T(A)[M,K] x B[N,K]^T  with split-bf16 3-pass MFMA.
// AMODE 0: a=clip(a)   (free phase)
// AMODE 1: a=a*bladeSign(k&7)   (logits)
template <int AMODE>
__global__ __launch_bounds__(256) void k_gemm_split(const float* __restrict__ A,
                                                    const float* __restrict__ B,
                                                    float* __restrict__ C, int ldc) {
  __shared__ unsigned short Ah[128 * 32], Al[128 * 32];
  __shared__ unsigned short Bh[128 * 32], Bl[128 * 32];
  const int t = threadIdx.x;
  const int row0 = blockIdx.y * 128, col0 = blockIdx.x * 128;
  const int l = t & 63, w = t >> 6;
  const int wr = w >> 1, wc = w & 1;
  const int sr = t >> 3;            // 0..31 (staging row base)
  const int cc = (t & 7) << 2;      // staging col base (fp32 elems)
  const int chunkb = cc >> 3;       // 16B-chunk index within row (0..3)
  const int halfo = (cc >> 2) & 1;  // low/high half of chunk

  f32x4 acc[4][4];
#pragma unroll
  for (int i = 0; i < 4; ++i)
#pragma unroll
    for (int j = 0; j < 4; ++j) acc[i][j] = (f32x4)0.f;

  const float sA0 = 1.f;
  const float sA1 = (cc & 4) ? -1.f : 1.f;
  const float sA2 = sA1;
  const float sA3 = -1.f;

  for (int k0 = 0; k0 < KDIM; k0 += 32) {
    float4 va[4], vb[4];
#pragma unroll
    for (int i = 0; i < 4; ++i) {
      va[i] = *(const float4*)(A + (size_t)(row0 + sr + i * 32) * KDIM + k0 + cc);
      vb[i] = *(const float4*)(B + (size_t)(col0 + sr + i * 32) * KDIM + k0 + cc);
    }
    __syncthreads();
#pragma unroll
    for (int i = 0; i < 4; ++i) {
      int row = sr + i * 32;
      int idx = row * 32 + ((chunkb ^ (row & 3)) << 3) + (halfo << 2);
      float4 a = va[i];
      if (AMODE == 0) {
        a.x = clipf(a.x); a.y = clipf(a.y); a.z = clipf(a.z); a.w = clipf(a.w);
      } else {
        a.x *= sA0; a.y *= sA1; a.z *= sA2; a.w *= sA3;
      }
      ushort4 h4, l4;
      h4.x = f2bf(a.x); l4.x = f2bf(a.x - bf2f(h4.x));
      h4.y = f2bf(a.y); l4.y = f2bf(a.y - bf2f(h4.y));
      h4.z = f2bf(a.z); l4.z = f2bf(a.z - bf2f(h4.z));
      h4.w = f2bf(a.w); l4.w = f2bf(a.w - bf2f(h4.w));
      *(ushort4*)&Ah[idx] = h4;
      *(ushort4*)&Al[idx] = l4;
      float4 b = vb[i];
      h4.x = f2bf(b.x); l4.x = f2bf(b.x - bf2f(h4.x));
      h4.y = f2bf(b.y); l4.y = f2bf(b.y - bf2f(h4.y));
      h4.z = f2bf(b.z); l4.z = f2bf(b.z - bf2f(h4.z));
      h4.w = f2bf(b.w); l4.w = f2bf(b.w - bf2f(h4.w));
      *(ushort4*)&Bh[idx] = h4;
      *(ushort4*)&Bl[idx] = l4;
    }
    __syncthreads();

    short8 ah[4], al[4], bh[4], bl[4];
#pragma unroll
    for (int mi = 0; mi < 4; ++mi) {
      int ar = wr * 64 + mi * 16 + (l & 15);
      int kc = (l >> 4) ^ (ar & 3);
      ah[mi] = *(short8*)&Ah[ar * 32 + kc * 8];
      al[mi] = *(short8*)&Al[ar * 32 + kc * 8];
      int br = wc * 64 + mi * 16 + (l & 15);
      int kb = (l >> 4) ^ (br & 3);
      bh[mi] = *(short8*)&Bh[br * 32 + kb * 8];
      bl[mi] = *(short8*)&Bl[br * 32 + kb * 8];
    }
#pragma unroll
    for (int mi = 0; mi < 4; ++mi)
#pragma unroll
      for (int ni = 0; ni < 4; ++ni) {
        acc[mi][ni] = __builtin_amdgcn_mfma_f32_16x16x32_bf16(ah[mi], bh[ni], acc[mi][ni], 0, 0, 0);
        acc[mi][ni] = __builtin_amdgcn_mfma_f32_16x16x32_bf16(ah[mi], bl[ni], acc[mi][ni], 0, 0, 0);
        acc[mi][ni] = __builtin_amdgcn_mfma_f32_16x16x32_bf16(al[mi], bh[ni], acc[mi][ni], 0, 0, 0);
      }
  }

#pragma unroll
  for (int mi = 0; mi < 4; ++mi)
#pragma unroll
    for (int ni = 0; ni < 4; ++ni) {
      int rg = row0 + wr * 64 + mi * 16 + (l >> 4) * 4;
      int cg = col0 + wc * 64 + ni * 16 + (l & 15);
#pragma unroll
      for (int j = 0; j < 4; ++j)
        C[(size_t)(rg + j) * ldc + cg] = acc[mi][ni][j];
    }
}

// h <- h - 0.1*(h - drho(h)*(inmv*sq + rec_prev*sq + fwd_next))
__global__ void k_update(float* __restrict__ Hb, const float* __restrict__ Imv,
                         const float* __restrict__ RF) {
  int idx = blockIdx.x * blockDim.x + threadIdx.x;
  int r = idx >> 11;
  int c = idx & 2047;
  int m = r & (LLEN - 1);
  int q = c & 7;
  float h = Hb[idx];
  float dr = (h > 0.f && h < 1.f) ? 1.f : ((h == 0.f || h == 1.f) ? 0.5f : 0.f);
  float sq = cl3_sign(q, q);
  float f = Imv[idx] * sq;
  if (m >= 1)        f += RF[(size_t)(r - 1) * NCOL + c] * sq;
  if (m < LLEN - 1)  f += RF[(size_t)(r + 1) * NCOL + KDIM + c];
  Hb[idx] = h - 0.1f * (h - dr * f);
}

extern "C" void kernel_launch(void* const* d_in, const int* in_sizes, int n_in,
                              void* d_out, int out_size, void* d_ws, size_t ws_size,
                              hipStream_t stream) {
  const int*   x    = (const int*)d_in[0];
  const float* emb  = (const float*)d_in[1];
  const float* Win  = (const float*)d_in[2];
  const float* Wrec = (const float*)d_in[3];
  const float* Wout = (const float*)d_in[4];
  float* logits = (float*)d_out;

  float* ws   = (float*)d_ws;
  float* Hbuf = ws;                 // 2,097,152 f  (8 MB)
  float* Imv  = ws + 2097152;       // 2,097,152 f  (8 MB)
  float* RF   = ws + 4194304;       // 4,194,304 f  (16 MB)
  float* MRT  = ws + 8388608;       // 8,388,608 f  (32 MB)  [N=4096][K=2048]

  hipMemsetAsync(Hbuf, 0, (size_t)2097152 * sizeof(float), stream);
  k_build_mrt<<<32768, 256, 0, stream>>>(Wrec, MRT);
  k_input_mv<<<256, 256, 0, stream>>>(x, emb, Win, Imv);
  for (int it = 0; it < 5; ++it) {
    k_gemm_split<0><<<dim3(NCOL / 128, NROWS / 128), 256, 0, stream>>>(Hbuf, MRT, RF, NCOL);
    k_update<<<8192, 256, 0, stream>>>(Hbuf, Imv, RF);
  }
  k_gemm_split<1><<<dim3(VOCAB / 128, NROWS / 128), 256, 0, stream>>>(Hbuf, Wout, logits, VOCAB);
}

// Round 3
// 888.115 us; speedup vs baseline: 3.5716x; 1.3383x over previous
//
#include <hip/hip_runtime.h>
#include <cstddef>
#include <cstdint>

#define VOCAB  32000
#define EMB    256
#define NB     8
#define KDIM   2048        /* H*NB */
#define NROWS  1024        /* B*L  */
#define NCOL   4096        /* 2*KDIM */
#define LLEN   256

typedef __attribute__((ext_vector_type(8))) short short8;
typedef __attribute__((ext_vector_type(4))) float f32x4;

__device__ __forceinline__ float cl3_sign(int a, int b) {
  int x = a >> 1, p = 0;
  while (x) { p ^= __popc(x & b) & 1; x >>= 1; }
  return p ? -1.f : 1.f;   // metric all +1 for Cl(3,0)
}

__device__ __forceinline__ float clipf(float v) { return fminf(fmaxf(v, 0.f), 1.f); }

__device__ __forceinline__ unsigned short f2bf(float f) {
  unsigned u = __float_as_uint(f);
  u += 0x7FFF + ((u >> 16) & 1);           // round-to-nearest-even
  return (unsigned short)(u >> 16);
}
__device__ __forceinline__ float bf2f(unsigned short h) {
  return __uint_as_float(((unsigned)h) << 16);
}

__device__ __forceinline__ int swz4(int r) { return (r ^ (r >> 2)) & 3; }

// tiled-swizzled element offset: row-tile tr (128 rows), k-tile tk (32 k), row in tile r, k in tile kk
__device__ __forceinline__ size_t tso(int tr, int tk, int r, int kk) {
  return ((size_t)(tr * 64 + tk) * 4096) + r * 32 + (((kk >> 3) ^ swz4(r)) << 3) + (kk & 7);
}

__device__ __forceinline__ void gload16(const void* g, void* l) {
  __builtin_amdgcn_global_load_lds((const __attribute__((address_space(1))) uint32_t*)g,
                                   (__attribute__((address_space(3))) uint32_t*)l, 16, 0, 0);
}

// ---- MRT split build: B^T [4096][2048], tiled-swizzled hi/lo bf16 ----
__global__ void k_build_mrt_split(const float* __restrict__ Wrec,
                                  unsigned short* __restrict__ Mhi,
                                  unsigned short* __restrict__ Mlo) {
  int idx = blockIdx.x * blockDim.x + threadIdx.x;
  int k = idx & (KDIM - 1);
  int n = idx >> 11;
  int h = k >> 3, i = k & 7;
  float v;
  if (n < KDIM) {
    int g = n >> 3, kb = n & 7;
    int j = i ^ kb;
    v = Wrec[(size_t)g * KDIM + h * NB + j] * cl3_sign(i, j);
  } else {
    int c = n - KDIM;
    int p = c >> 3, q = c & 7;
    int j = q ^ i;
    v = cl3_sign(i, i) * cl3_sign(q, j) * Wrec[(size_t)h * KDIM + p * NB + j];
  }
  unsigned short hi = f2bf(v);
  unsigned short lo = f2bf(v - bf2f(hi));
  size_t off = tso(n >> 7, k >> 5, n & 127, k & 31);
  Mhi[off] = hi; Mlo[off] = lo;
}

// ---- Wout converter: [32000][2048] fp32 -> tiled-swizzled hi/lo ----
__global__ __launch_bounds__(256) void k_conv_wout(const float* __restrict__ W,
                                                   unsigned short* __restrict__ Whi,
                                                   unsigned short* __restrict__ Wlo) {
  size_t idx = (size_t)blockIdx.x * 256 + threadIdx.x;   // 8,192,000 threads
  int v = (int)(idx >> 8);
  int c = (int)(idx & 255) << 3;
  const float* src = W + (size_t)v * KDIM + c;
  float4 a = *(const float4*)src;
  float4 b = *(const float4*)(src + 4);
  float e[8] = {a.x, a.y, a.z, a.w, b.x, b.y, b.z, b.w};
  short8 h8, l8;
#pragma unroll
  for (int j = 0; j < 8; ++j) {
    unsigned short hi = f2bf(e[j]);
    h8[j] = (short)hi;
    l8[j] = (short)f2bf(e[j] - bf2f(hi));
  }
  size_t off = tso(v >> 7, c >> 5, v & 127, c & 31);
  *(short8*)&Whi[off] = h8;
  *(short8*)&Wlo[off] = l8;
}

// input_mv[r][h*8+i] = sum_d emb[x[r]][d] * Win[h][d][i]; one block = 4 rows
__global__ __launch_bounds__(256) void k_input_mv(const int* __restrict__ x,
                                                  const float* __restrict__ emb,
                                                  const float* __restrict__ Win,
                                                  float* __restrict__ out) {
  __shared__ float se[4][EMB];
  int r0 = blockIdx.x * 4;
  int t = threadIdx.x;
  for (int rr = 0; rr < 4; ++rr) {
    int tok = x[r0 + rr];
    se[rr][t] = emb[(size_t)tok * EMB + t];
  }
  __syncthreads();
  float acc[4][8];
#pragma unroll
  for (int rr = 0; rr < 4; ++rr)
#pragma unroll
    for (int i = 0; i < 8; ++i) acc[rr][i] = 0.f;
  const float* wrow = Win + (size_t)t * KDIM;
  for (int d = 0; d < EMB; ++d) {
    float4 w0 = *(const float4*)(wrow + d * 8);
    float4 w1 = *(const float4*)(wrow + d * 8 + 4);
#pragma unroll
    for (int rr = 0; rr < 4; ++rr) {
      float e = se[rr][d];
      acc[rr][0] += e * w0.x; acc[rr][1] += e * w0.y;
      acc[rr][2] += e * w0.z; acc[rr][3] += e * w0.w;
      acc[rr][4] += e * w1.x; acc[rr][5] += e * w1.y;
      acc[rr][6] += e * w1.z; acc[rr][7] += e * w1.w;
    }
  }
  for (int rr = 0; rr < 4; ++rr) {
    float4* o = (float4*)(out + (size_t)(r0 + rr) * KDIM + t * 8);
    o[0] = make_float4(acc[rr][0], acc[rr][1], acc[rr][2], acc[rr][3]);
    o[1] = make_float4(acc[rr][4], acc[rr][5], acc[rr][6], acc[rr][7]);
  }
}

// ---- pure bf16 split GEMM: C[M,*] += (Ahi+Alo)(Bhi+Blo)^T, 3-pass MFMA ----
// A tiled arrays: 8 row-tiles x 64 k-tiles; B: (nwg/8) row-tiles x 64 k-tiles.
__global__ __launch_bounds__(256, 2) void k_gemm_pre(const unsigned short* __restrict__ Ahi,
                                                     const unsigned short* __restrict__ Alo,
                                                     const unsigned short* __restrict__ Bhi,
                                                     const unsigned short* __restrict__ Blo,
                                                     float* __restrict__ C, int ldc) {
  __shared__ __align__(16) unsigned short lds[2][4][4096];
  const int nwg = gridDim.x;
  const int b = blockIdx.x;
  const int lin = (b & 7) * (nwg >> 3) + (b >> 3);   // XCD-chunked swizzle (nwg%8==0)
  const int tn = lin >> 3, tm = lin & 7;             // 8 consecutive lin share B-panel
  const int t = threadIdx.x;
  const int l = t & 63, w = t >> 6;
  const int wr = w >> 1, wc = w & 1;

  const unsigned short* aH = Ahi + (size_t)tm * 64 * 4096;
  const unsigned short* aL = Alo + (size_t)tm * 64 * 4096;
  const unsigned short* bH = Bhi + (size_t)tn * 64 * 4096;
  const unsigned short* bL = Blo + (size_t)tn * 64 * 4096;

  const int ldso0 = (w * 2) * 512;        // ushort units, wave-uniform
  const int ldso1 = (w * 2 + 1) * 512;
  const int srco0 = ldso0 + l * 8;
  const int srco1 = ldso1 + l * 8;

  const int arA = wr * 64 + (l & 15);
  const int arB = wc * 64 + (l & 15);
  const int c0 = l >> 4;

  f32x4 acc[4][4];
#pragma unroll
  for (int i = 0; i < 4; ++i)
#pragma unroll
    for (int j = 0; j < 4; ++j) acc[i][j] = (f32x4)0.f;

  auto STAGE = [&](int bf, int kt) {
    size_t kb = (size_t)kt * 4096;
    gload16(aH + kb + srco0, &lds[bf][0][ldso0]);
    gload16(aH + kb + srco1, &lds[bf][0][ldso1]);
    gload16(aL + kb + srco0, &lds[bf][1][ldso0]);
    gload16(aL + kb + srco1, &lds[bf][1][ldso1]);
    gload16(bH + kb + srco0, &lds[bf][2][ldso0]);
    gload16(bH + kb + srco1, &lds[bf][2][ldso1]);
    gload16(bL + kb + srco0, &lds[bf][3][ldso0]);
    gload16(bL + kb + srco1, &lds[bf][3][ldso1]);
  };

  STAGE(0, 0);
  __syncthreads();
  int cur = 0;
  for (int kt = 0; kt < 64; ++kt) {
    if (kt < 63) STAGE(cur ^ 1, kt + 1);
    short8 ah[4], al[4], bh[4], bl[4];
#pragma unroll
    for (int mi = 0; mi < 4; ++mi) {
      int ra = arA + mi * 16;
      int oa = ra * 32 + ((c0 ^ swz4(ra)) << 3);
      ah[mi] = *(const short8*)&lds[cur][0][oa];
      al[mi] = *(const short8*)&lds[cur][1][oa];
      int rb = arB + mi * 16;
      int ob = rb * 32 + ((c0 ^ swz4(rb)) << 3);
      bh[mi] = *(const short8*)&lds[cur][2][ob];
      bl[mi] = *(const short8*)&lds[cur][3][ob];
    }
#pragma unroll
    for (int mi = 0; mi < 4; ++mi)
#pragma unroll
      for (int ni = 0; ni < 4; ++ni) {
        acc[mi][ni] = __builtin_amdgcn_mfma_f32_16x16x32_bf16(ah[mi], bh[ni], acc[mi][ni], 0, 0, 0);
        acc[mi][ni] = __builtin_amdgcn_mfma_f32_16x16x32_bf16(ah[mi], bl[ni], acc[mi][ni], 0, 0, 0);
        acc[mi][ni] = __builtin_amdgcn_mfma_f32_16x16x32_bf16(al[mi], bh[ni], acc[mi][ni], 0, 0, 0);
      }
    __syncthreads();
    cur ^= 1;
  }

  const int rg0 = tm * 128 + wr * 64 + (l >> 4) * 4;
  const int cg0 = tn * 128 + wc * 64 + (l & 15);
#pragma unroll
  for (int mi = 0; mi < 4; ++mi)
#pragma unroll
    for (int ni = 0; ni < 4; ++ni)
#pragma unroll
      for (int j = 0; j < 4; ++j)
        C[(size_t)(rg0 + mi * 16 + j) * ldc + cg0 + ni * 16] = acc[mi][ni][j];
}

// h <- h - 0.1*(h - drho(h)*(inmv*sq + rec_prev*sq + fwd_next)); emits split A for next GEMM
template <int LAST>
__global__ __launch_bounds__(256) void k_update(float* __restrict__ Hb, const float* __restrict__ Imv,
                                                const float* __restrict__ RF,
                                                unsigned short* __restrict__ Hhi,
                                                unsigned short* __restrict__ Hlo) {
  int idx = blockIdx.x * 256 + threadIdx.x;   // 262144 threads, 8 elems each
  int r = idx >> 8;
  int c = (idx & 255) << 3;
  int m = r & (LLEN - 1);
  const size_t base = (size_t)r * KDIM + c;
  float h[8], f[8];
  *(float4*)&h[0] = *(const float4*)(Hb + base);
  *(float4*)&h[4] = *(const float4*)(Hb + base + 4);
  float4 i0 = *(const float4*)(Imv + base);
  float4 i1 = *(const float4*)(Imv + base + 4);
  f[0] = i0.x; f[1] = i0.y; f[2] = i0.z; f[3] = i0.w;
  f[4] = i1.x; f[5] = i1.y; f[6] = i1.z; f[7] = i1.w;
#pragma unroll
  for (int j = 0; j < 8; ++j) f[j] *= ((0xE8 >> j) & 1) ? -1.f : 1.f;
  if (m >= 1) {
    const float* rp = RF + (size_t)(r - 1) * NCOL + c;
    float4 p0 = *(const float4*)rp;
    float4 p1 = *(const float4*)(rp + 4);
    float p[8] = {p0.x, p0.y, p0.z, p0.w, p1.x, p1.y, p1.z, p1.w};
#pragma unroll
    for (int j = 0; j < 8; ++j) f[j] += p[j] * (((0xE8 >> j) & 1) ? -1.f : 1.f);
  }
  if (m < LLEN - 1) {
    const float* rn = RF + (size_t)(r + 1) * NCOL + KDIM + c;
    float4 n0 = *(const float4*)rn;
    float4 n1 = *(const float4*)(rn + 4);
    f[0] += n0.x; f[1] += n0.y; f[2] += n0.z; f[3] += n0.w;
    f[4] += n1.x; f[5] += n1.y; f[6] += n1.z; f[7] += n1.w;
  }
  float hn[8];
  short8 h8, l8;
#pragma unroll
  for (int j = 0; j < 8; ++j) {
    float hv = h[j];
    float dr = (hv > 0.f && hv < 1.f) ? 1.f : ((hv == 0.f || hv == 1.f) ? 0.5f : 0.f);
    hn[j] = hv - 0.1f * (hv - dr * f[j]);
    float av = LAST ? hn[j] * (((0xE8 >> j) & 1) ? -1.f : 1.f) : clipf(hn[j]);
    unsigned short hi = f2bf(av);
    h8[j] = (short)hi;
    l8[j] = (short)f2bf(av - bf2f(hi));
  }
  *(float4*)(Hb + base) = make_float4(hn[0], hn[1], hn[2], hn[3]);
  *(float4*)(Hb + base + 4) = make_float4(hn[4], hn[5], hn[6], hn[7]);
  size_t off = tso(r >> 7, c >> 5, r & 127, c & 31);
  *(short8*)&Hhi[off] = h8;
  *(short8*)&Hlo[off] = l8;
}

// ---- round-2 fallback logits GEMM (in-kernel conversion), used if ws too small ----
template <int AMODE>
__global__ __launch_bounds__(256) void k_gemm_split(const float* __restrict__ A,
                                                    const float* __restrict__ B,
                                                    float* __restrict__ C, int ldc) {
  __shared__ unsigned short Ah[128 * 32], Al[128 * 32];
  __shared__ unsigned short Bh[128 * 32], Bl[128 * 32];
  const int t = threadIdx.x;
  const int row0 = blockIdx.y * 128, col0 = blockIdx.x * 128;
  const int l = t & 63, w = t >> 6;
  const int wr = w >> 1, wc = w & 1;
  const int sr = t >> 3;
  const int cc = (t & 7) << 2;
  const int chunkb = cc >> 3;
  const int halfo = (cc >> 2) & 1;
  f32x4 acc[4][4];
#pragma unroll
  for (int i = 0; i < 4; ++i)
#pragma unroll
    for (int j = 0; j < 4; ++j) acc[i][j] = (f32x4)0.f;
  const float sA0 = 1.f;
  const float sA1 = (cc & 4) ? -1.f : 1.f;
  const float sA2 = sA1;
  const float sA3 = -1.f;
  for (int k0 = 0; k0 < KDIM; k0 += 32) {
    float4 va[4], vb[4];
#pragma unroll
    for (int i = 0; i < 4; ++i) {
      va[i] = *(const float4*)(A + (size_t)(row0 + sr + i * 32) * KDIM + k0 + cc);
      vb[i] = *(const float4*)(B + (size_t)(col0 + sr + i * 32) * KDIM + k0 + cc);
    }
    __syncthreads();
#pragma unroll
    for (int i = 0; i < 4; ++i) {
      int row = sr + i * 32;
      int idx = row * 32 + ((chunkb ^ (row & 3)) << 3) + (halfo << 2);
      float4 a = va[i];
      if (AMODE == 0) {
        a.x = clipf(a.x); a.y = clipf(a.y); a.z = clipf(a.z); a.w = clipf(a.w);
      } else {
        a.x *= sA0; a.y *= sA1; a.z *= sA2; a.w *= sA3;
      }
      ushort4 h4, l4;
      h4.x = f2bf(a.x); l4.x = f2bf(a.x - bf2f(h4.x));
      h4.y = f2bf(a.y); l4.y = f2bf(a.y - bf2f(h4.y));
      h4.z = f2bf(a.z); l4.z = f2bf(a.z - bf2f(h4.z));
      h4.w = f2bf(a.w); l4.w = f2bf(a.w - bf2f(h4.w));
      *(ushort4*)&Ah[idx] = h4;
      *(ushort4*)&Al[idx] = l4;
      float4 bb = vb[i];
      h4.x = f2bf(bb.x); l4.x = f2bf(bb.x - bf2f(h4.x));
      h4.y = f2bf(bb.y); l4.y = f2bf(bb.y - bf2f(h4.y));
      h4.z = f2bf(bb.z); l4.z = f2bf(bb.z - bf2f(h4.z));
      h4.w = f2bf(bb.w); l4.w = f2bf(bb.w - bf2f(h4.w));
      *(ushort4*)&Bh[idx] = h4;
      *(ushort4*)&Bl[idx] = l4;
    }
    __syncthreads();
    short8 ah[4], al[4], bh[4], bl[4];
#pragma unroll
    for (int mi = 0; mi < 4; ++mi) {
      int ar = wr * 64 + mi * 16 + (l & 15);
      int kc = (l >> 4) ^ (ar & 3);
      ah[mi] = *(short8*)&Ah[ar * 32 + kc * 8];
      al[mi] = *(short8*)&Al[ar * 32 + kc * 8];
      int br = wc * 64 + mi * 16 + (l & 15);
      int kb = (l >> 4) ^ (br & 3);
      bh[mi] = *(short8*)&Bh[br * 32 + kb * 8];
      bl[mi] = *(short8*)&Bl[br * 32 + kb * 8];
    }
#pragma unroll
    for (int mi = 0; mi < 4; ++mi)
#pragma unroll
      for (int ni = 0; ni < 4; ++ni) {
        acc[mi][ni] = __builtin_amdgcn_mfma_f32_16x16x32_bf16(ah[mi], bh[ni], acc[mi][ni], 0, 0, 0);
        acc[mi][ni] = __builtin_amdgcn_mfma_f32_16x16x32_bf16(ah[mi], bl[ni], acc[mi][ni], 0, 0, 0);
        acc[mi][ni] = __builtin_amdgcn_mfma_f32_16x16x32_bf16(al[mi], bh[ni], acc[mi][ni], 0, 0, 0);
      }
  }
#pragma unroll
  for (int mi = 0; mi < 4; ++mi)
#pragma unroll
    for (int ni = 0; ni < 4; ++ni) {
      int rg = row0 + wr * 64 + mi * 16 + (l >> 4) * 4;
      int cg = col0 + wc * 64 + ni * 16 + (l & 15);
#pragma unroll
      for (int j = 0; j < 4; ++j)
        C[(size_t)(rg + j) * ldc + cg] = acc[mi][ni][j];
    }
}

extern "C" void kernel_launch(void* const* d_in, const int* in_sizes, int n_in,
                              void* d_out, int out_size, void* d_ws, size_t ws_size,
                              hipStream_t stream) {
  const int*   x    = (const int*)d_in[0];
  const float* emb  = (const float*)d_in[1];
  const float* Win  = (const float*)d_in[2];
  const float* Wrec = (const float*)d_in[3];
  const float* Wout = (const float*)d_in[4];
  float* logits = (float*)d_out;

  float* ws   = (float*)d_ws;
  float* Hbuf = ws;                          // 2M f   ( 8 MB)
  float* Imv  = ws + (1 << 21);              // 2M f   ( 8 MB)
  float* RF   = ws + (1 << 22);              // 4M f   (16 MB)
  unsigned short* Hhi = (unsigned short*)(ws + (1 << 23));   // 2M ush (4 MB)
  unsigned short* Hlo = Hhi + (1 << 21);                     // 2M ush
  unsigned short* Mhi = Hlo + (1 << 21);                     // 8M ush (16 MB)
  unsigned short* Mlo = Mhi + (1 << 23);                     // 8M ush
  unsigned short* Whi = Mlo + (1 << 23);                     // 65.536M ush (131 MB)
  unsigned short* Wlo = Whi + (size_t)VOCAB * KDIM;

  const size_t need = (size_t)75497472 + 2ull * VOCAB * KDIM * sizeof(unsigned short);
  const bool big = ws_size >= need;

  hipMemsetAsync(Hbuf, 0, (size_t)8 << 20, stream);
  hipMemsetAsync(Hhi, 0, (size_t)8 << 20, stream);   // Hhi + Hlo contiguous
  k_build_mrt_split<<<32768, 256, 0, stream>>>(Wrec, Mhi, Mlo);
  k_input_mv<<<256, 256, 0, stream>>>(x, emb, Win, Imv);
  if (big) k_conv_wout<<<32000, 256, 0, stream>>>(Wout, Whi, Wlo);

  for (int it = 0; it < 5; ++it) {
    k_gemm_pre<<<256, 256, 0, stream>>>(Hhi, Hlo, Mhi, Mlo, RF, NCOL);
    if (it < 4) k_update<0><<<1024, 256, 0, stream>>>(Hbuf, Imv, RF, Hhi, Hlo);
    else        k_update<1><<<1024, 256, 0, stream>>>(Hbuf, Imv, RF, Hhi, Hlo);
  }

  if (big) k_gemm_pre<<<2000, 256, 0, stream>>>(Hhi, Hlo, Whi, Wlo, logits, VOCAB);
  else     k_gemm_split<1><<<dim3(VOCAB / 128, NROWS / 128), 256, 0, stream>>>(Hbuf, Wout, logits, VOCAB);
}